// Round 2
// baseline (382.984 us; speedup 1.0000x reference)
//
#include <hip/hip_runtime.h>

typedef __bf16 bf16;
typedef __bf16 bf16x8 __attribute__((ext_vector_type(8)));
typedef float f32x4 __attribute__((ext_vector_type(4)));

#define MFMA16(a,b,c) __builtin_amdgcn_mfma_f32_16x16x32_bf16((a),(b),(c),0,0,0)

// Shapes (fixed): B=32, N=384, C=768, H=12, Dh=64, mt=128, 2B=64 batches.
// All global inputs/outputs are FLOAT32. Intermediates (Q/K/V/ATT) are bf16.
// Q/K/V ws layout: [b'(64)][h(12)][tok(384)][d(64)] bf16.
// ATT ws layout: [b'*384+tok][h*64+d] = (24576 x 768) bf16.

__device__ inline bf16x8 cvt8(const float* p) {
  f32x4 a = *(const f32x4*)p;
  f32x4 b = *(const f32x4*)(p + 4);
  bf16x8 r;
  r[0] = (bf16)a[0]; r[1] = (bf16)a[1]; r[2] = (bf16)a[2]; r[3] = (bf16)a[3];
  r[4] = (bf16)b[0]; r[5] = (bf16)b[1]; r[6] = (bf16)b[2]; r[7] = (bf16)b[3];
  return r;
}

// ---------------------------------------------------------------------------
// Kernel 1: QKV projection.  C = X @ W^T, scatter into Q (scaled 0.125), K, V.
// 128x128 tile, BK=32, 4 waves, each wave 64x64 (4x4 fragments).
// ---------------------------------------------------------------------------
__global__ __launch_bounds__(256) void qkv_kernel(
    const float* __restrict__ xv, const float* __restrict__ xi,
    const float* __restrict__ w,
    bf16* __restrict__ Qo, bf16* __restrict__ Ko, bf16* __restrict__ Vo)
{
  __shared__ bf16 As[128][40];
  __shared__ bf16 Bs[128][40];
  const int m0 = blockIdx.x * 128;
  const int n0 = blockIdx.y * 128;
  const int tid = threadIdx.x;
  const int lane = tid & 63;
  const int wv = tid >> 6;
  const int wr = (wv >> 1) * 64, wc = (wv & 1) * 64;
  const int lr = lane & 15, lg = lane >> 4;

  f32x4 acc[4][4] = {};

  for (int kt = 0; kt < 768; kt += 32) {
#pragma unroll
    for (int i = 0; i < 2; ++i) {
      int v = tid + i * 256;             // 0..511
      int row = v >> 2, cg = (v & 3) * 8;
      int gm = m0 + row;
      const float* src = (gm < 12288) ? (xv + (size_t)gm * 768)
                                      : (xi + (size_t)(gm - 12288) * 768);
      *(bf16x8*)(&As[row][cg]) = cvt8(src + kt + cg);
      *(bf16x8*)(&Bs[row][cg]) = cvt8(w + (size_t)(n0 + row) * 768 + kt + cg);
    }
    __syncthreads();
    bf16x8 af[4], bfr[4];
#pragma unroll
    for (int mf = 0; mf < 4; ++mf) af[mf] = *(const bf16x8*)(&As[wr + mf * 16 + lr][lg * 8]);
#pragma unroll
    for (int nf = 0; nf < 4; ++nf) bfr[nf] = *(const bf16x8*)(&Bs[wc + nf * 16 + lr][lg * 8]);
#pragma unroll
    for (int mf = 0; mf < 4; ++mf)
#pragma unroll
      for (int nf = 0; nf < 4; ++nf)
        acc[mf][nf] = MFMA16(af[mf], bfr[nf], acc[mf][nf]);
    __syncthreads();
  }

#pragma unroll
  for (int mf = 0; mf < 4; ++mf)
#pragma unroll
    for (int nf = 0; nf < 4; ++nf)
#pragma unroll
      for (int r = 0; r < 4; ++r) {
        int m = m0 + wr + mf * 16 + lg * 4 + r;
        int n = n0 + wc + nf * 16 + lr;
        int bp = m / 384, tok = m - bp * 384;
        int comp = (n >= 1536) ? 2 : (n >= 768) ? 1 : 0;
        int rem = n - comp * 768;
        int hh = rem >> 6, d = rem & 63;
        size_t addr = (((size_t)bp * 12 + hh) * 384 + tok) * 64 + d;
        float val = acc[mf][nf][r];
        if (comp == 0)      Qo[addr] = (bf16)(val * 0.125f);   // fold 1/sqrt(Dh)
        else if (comp == 1) Ko[addr] = (bf16)val;
        else                Vo[addr] = (bf16)val;
      }
}

// ---------------------------------------------------------------------------
// Kernel 2: attention. grid = 64(b') * 12(h) * 3(qblock of 128 queries).
//  qb==0: mt queries 0..127, keys = own-stream mt (1 chunk of 128).
//  qb>=1: s queries, keys = [mt of V-batch, mt of I-batch, own s0, own s1].
// 4 waves * 32 q-rows; flash-style online softmax; P via LDS for layout swap.
// ---------------------------------------------------------------------------
__global__ __launch_bounds__(256) void attn_kernel(
    const bf16* __restrict__ Q, const bf16* __restrict__ K, const bf16* __restrict__ V,
    bf16* __restrict__ ATT)
{
  __shared__ union {
    bf16 Qs[128][72];
    bf16 Ps[4][32][136];     // per-wave P tile (Qs dead after qf reg-cache)
  } u;
  __shared__ bf16 Ks[128][72];
  __shared__ bf16 VTs[64][136];     // transposed V: [d][token]

  const int bid = blockIdx.x;
  const int qb = bid % 3;
  const int h  = (bid / 3) % 12;
  const int bp = bid / 36;           // b' in [0,64)
  const int tid = threadIdx.x;
  const int lane = tid & 63;
  const int wv = tid >> 6;
  const int lr = lane & 15, lg = lane >> 4;

  const size_t bh384 = ((size_t)bp * 12 + h) * 384;
  const int q0 = qb * 128;

  for (int v = tid; v < 1024; v += 256) {
    int row = v >> 3, cg = (v & 7) * 8;
    *(bf16x8*)(&u.Qs[row][cg]) = *(const bf16x8*)(Q + (bh384 + q0 + row) * 64 + cg);
  }
  __syncthreads();

  bf16x8 qf[2][2];
#pragma unroll
  for (int mf = 0; mf < 2; ++mf)
#pragma unroll
    for (int ks = 0; ks < 2; ++ks)
      qf[mf][ks] = *(const bf16x8*)(&u.Qs[wv * 32 + mf * 16 + lr][ks * 32 + lg * 8]);

  f32x4 O[2][4] = {};
  float runmax[2][4], runsum[2][4];
#pragma unroll
  for (int mf = 0; mf < 2; ++mf)
#pragma unroll
    for (int r = 0; r < 4; ++r) { runmax[mf][r] = -1e30f; runsum[mf][r] = 0.f; }

  const int nchunks = (qb == 0) ? 1 : 4;
  for (int c = 0; c < nchunks; ++c) {
    int src_b, t0;
    if (qb == 0)      { src_b = bp;            t0 = 0; }
    else if (c == 0)  { src_b = bp & 31;       t0 = 0; }          // mt of V batch
    else if (c == 1)  { src_b = (bp & 31)+32;  t0 = 0; }          // mt of I batch
    else              { src_b = bp;            t0 = (c - 1) * 128; } // own s tokens
    const size_t kb = (((size_t)src_b * 12 + h) * 384 + t0) * 64;

    __syncthreads();   // previous chunk fully consumed before restaging
    for (int v = tid; v < 1024; v += 256) {
      int row = v >> 3, cg = (v & 7) * 8;
      *(bf16x8*)(&Ks[row][cg]) = *(const bf16x8*)(K + kb + row * 64 + cg);
      bf16x8 vvld = *(const bf16x8*)(V + kb + row * 64 + cg);
#pragma unroll
      for (int j = 0; j < 8; ++j) VTs[cg + j][row] = vvld[j];
    }
    __syncthreads();

    // S = Q * Kc^T   (scale already folded into Q)
    f32x4 S[2][8] = {};
#pragma unroll
    for (int nf = 0; nf < 8; ++nf) {
#pragma unroll
      for (int ks = 0; ks < 2; ++ks) {
        bf16x8 kf = *(const bf16x8*)(&Ks[nf * 16 + lr][ks * 32 + lg * 8]);
        S[0][nf] = MFMA16(qf[0][ks], kf, S[0][nf]);
        S[1][nf] = MFMA16(qf[1][ks], kf, S[1][nf]);
      }
    }

    // online softmax (row = lg*4 + r within 16-row fragment; 16-lane reduce)
#pragma unroll
    for (int mf = 0; mf < 2; ++mf) {
#pragma unroll
      for (int r = 0; r < 4; ++r) {
        float mx = S[mf][0][r];
#pragma unroll
        for (int nf = 1; nf < 8; ++nf) mx = fmaxf(mx, S[mf][nf][r]);
        mx = fmaxf(mx, __shfl_xor(mx, 1));
        mx = fmaxf(mx, __shfl_xor(mx, 2));
        mx = fmaxf(mx, __shfl_xor(mx, 4));
        mx = fmaxf(mx, __shfl_xor(mx, 8));
        float nm = fmaxf(runmax[mf][r], mx);
        float rf = __expf(runmax[mf][r] - nm);
        float rs = 0.f;
#pragma unroll
        for (int nf = 0; nf < 8; ++nf) {
          float p = __expf(S[mf][nf][r] - nm);
          S[mf][nf][r] = p;
          rs += p;
        }
        rs += __shfl_xor(rs, 1);
        rs += __shfl_xor(rs, 2);
        rs += __shfl_xor(rs, 4);
        rs += __shfl_xor(rs, 8);
        runsum[mf][r] = runsum[mf][r] * rf + rs;
        runmax[mf][r] = nm;
#pragma unroll
        for (int vn = 0; vn < 4; ++vn) O[mf][vn][r] *= rf;
      }
    }

    // P (C-layout) -> LDS -> A-layout fragments.  Wave-private; DS in-order.
#pragma unroll
    for (int mf = 0; mf < 2; ++mf)
#pragma unroll
      for (int nf = 0; nf < 8; ++nf)
#pragma unroll
        for (int r = 0; r < 4; ++r)
          u.Ps[wv][mf * 16 + lg * 4 + r][nf * 16 + lr] = (bf16)S[mf][nf][r];

#pragma unroll
    for (int ks = 0; ks < 4; ++ks) {
      bf16x8 pf0 = *(const bf16x8*)(&u.Ps[wv][lr][ks * 32 + lg * 8]);
      bf16x8 pf1 = *(const bf16x8*)(&u.Ps[wv][16 + lr][ks * 32 + lg * 8]);
#pragma unroll
      for (int vn = 0; vn < 4; ++vn) {
        bf16x8 vf = *(const bf16x8*)(&VTs[vn * 16 + lr][ks * 32 + lg * 8]);
        O[0][vn] = MFMA16(pf0, vf, O[0][vn]);
        O[1][vn] = MFMA16(pf1, vf, O[1][vn]);
      }
    }
  }

#pragma unroll
  for (int mf = 0; mf < 2; ++mf)
#pragma unroll
    for (int vn = 0; vn < 4; ++vn)
#pragma unroll
      for (int r = 0; r < 4; ++r) {
        int tok = q0 + wv * 32 + mf * 16 + lg * 4 + r;
        int d = vn * 16 + lr;
        float o = O[mf][vn][r] / runsum[mf][r];
        ATT[((size_t)bp * 384 + tok) * 768 + h * 64 + d] = (bf16)o;
      }
}

// ---------------------------------------------------------------------------
// Kernel 3: output projection.  out = ATT @ proj_w^T + b  -> d_out (FLOAT32).
// ---------------------------------------------------------------------------
__global__ __launch_bounds__(256) void proj_kernel(
    const bf16* __restrict__ A, const float* __restrict__ w,
    const float* __restrict__ bias, float* __restrict__ out)
{
  __shared__ bf16 As[128][40];
  __shared__ bf16 Bs[128][40];
  const int m0 = blockIdx.x * 128;
  const int n0 = blockIdx.y * 128;
  const int tid = threadIdx.x;
  const int lane = tid & 63;
  const int wv = tid >> 6;
  const int wr = (wv >> 1) * 64, wc = (wv & 1) * 64;
  const int lr = lane & 15, lg = lane >> 4;

  f32x4 acc[4][4] = {};

  for (int kt = 0; kt < 768; kt += 32) {
#pragma unroll
    for (int i = 0; i < 2; ++i) {
      int v = tid + i * 256;
      int row = v >> 2, cg = (v & 3) * 8;
      *(bf16x8*)(&As[row][cg]) = *(const bf16x8*)(A + (size_t)(m0 + row) * 768 + kt + cg);
      *(bf16x8*)(&Bs[row][cg]) = cvt8(w + (size_t)(n0 + row) * 768 + kt + cg);
    }
    __syncthreads();
    bf16x8 af[4], bfr[4];
#pragma unroll
    for (int mf = 0; mf < 4; ++mf) af[mf] = *(const bf16x8*)(&As[wr + mf * 16 + lr][lg * 8]);
#pragma unroll
    for (int nf = 0; nf < 4; ++nf) bfr[nf] = *(const bf16x8*)(&Bs[wc + nf * 16 + lr][lg * 8]);
#pragma unroll
    for (int mf = 0; mf < 4; ++mf)
#pragma unroll
      for (int nf = 0; nf < 4; ++nf)
        acc[mf][nf] = MFMA16(af[mf], bfr[nf], acc[mf][nf]);
    __syncthreads();
  }

#pragma unroll
  for (int mf = 0; mf < 4; ++mf)
#pragma unroll
    for (int nf = 0; nf < 4; ++nf)
#pragma unroll
      for (int r = 0; r < 4; ++r) {
        int m = m0 + wr + mf * 16 + lg * 4 + r;
        int n = n0 + wc + nf * 16 + lr;
        out[(size_t)m * 768 + n] = acc[mf][nf][r] + bias[n];
      }
}

// ---------------------------------------------------------------------------
extern "C" void kernel_launch(void* const* d_in, const int* in_sizes, int n_in,
                              void* d_out, int out_size, void* d_ws, size_t ws_size,
                              hipStream_t stream) {
  (void)in_sizes; (void)n_in; (void)out_size;
  const float* xv     = (const float*)d_in[0];
  const float* xi     = (const float*)d_in[1];
  const float* qkv_w  = (const float*)d_in[2];
  const float* proj_w = (const float*)d_in[3];
  const float* proj_b = (const float*)d_in[4];
  float* out = (float*)d_out;

  // ws: Q | K | V | ATT, each 18874368 bf16 elems (~36 MB); total ~151 MB.
  const size_t SZ = (size_t)64 * 12 * 384 * 64;
  bf16* Q   = (bf16*)d_ws;
  bf16* K   = Q + SZ;
  bf16* V   = K + SZ;
  bf16* ATT = V + SZ;
  (void)ws_size;

  qkv_kernel<<<dim3(192, 18), 256, 0, stream>>>(xv, xi, qkv_w, Q, K, V);
  attn_kernel<<<dim3(64 * 12 * 3), 256, 0, stream>>>(Q, K, V, ATT);
  proj_kernel<<<dim3(192, 6), 256, 0, stream>>>(ATT, proj_w, proj_b, out);
}

// Round 3
// 339.143 us; speedup vs baseline: 1.1293x; 1.1293x over previous
//
#include <hip/hip_runtime.h>

typedef __bf16 bf16;
typedef __bf16 bf16x8 __attribute__((ext_vector_type(8)));
typedef float f32x4 __attribute__((ext_vector_type(4)));

#define MFMA16(a,b,c) __builtin_amdgcn_mfma_f32_16x16x32_bf16((a),(b),(c),0,0,0)

// Shapes (fixed): B=32, N=384, C=768, H=12, Dh=64, mt=128, 2B=64 batches.
// Global inputs/outputs are FLOAT32. Intermediates bf16.
// Xb (x as bf16, [24576][768]) + Wq (qkv_w bf16, [2304][768]) live in d_out
// (75.5 MB f32 out buffer used as scratch; fully overwritten by proj at end).
// ws: Q | K | V | ATT (each [64][12][384][64] / [24576][768] bf16) = 151 MB.
// proj_w bf16 (Wp) reuses the Q region after attn is done.

__device__ inline void gload16(const bf16* g, bf16* l) {
  __builtin_amdgcn_global_load_lds(
      (const __attribute__((address_space(1))) void*)g,
      (__attribute__((address_space(3))) void*)l, 16, 0, 0);
}

// ---------------------------------------------------------------------------
// convert1: pack xv | xi | qkv_w (f32) -> bf16 into d_out scratch.
// 20,643,840 elems total, 8 per thread.
// ---------------------------------------------------------------------------
__global__ __launch_bounds__(256) void convert1_kernel(
    const float* __restrict__ xv, const float* __restrict__ xi,
    const float* __restrict__ w, bf16* __restrict__ dst)
{
  const size_t NV = 9437184;     // 12288*768
  const size_t NX = 18874368;    // 2*NV
  const size_t NT = 20643840;    // NX + 2304*768/… (qkv_w = 1769472)
  for (size_t i = (size_t)blockIdx.x * 256 + threadIdx.x; i * 8 < NT;
       i += (size_t)gridDim.x * 256) {
    size_t e = i * 8;
    const float* src;
    if (e < NV)      src = xv + e;
    else if (e < NX) src = xi + (e - NV);
    else             src = w + (e - NX);
    f32x4 a = *(const f32x4*)src;
    f32x4 b = *(const f32x4*)(src + 4);
    bf16x8 r;
    r[0] = (bf16)a[0]; r[1] = (bf16)a[1]; r[2] = (bf16)a[2]; r[3] = (bf16)a[3];
    r[4] = (bf16)b[0]; r[5] = (bf16)b[1]; r[6] = (bf16)b[2]; r[7] = (bf16)b[3];
    *(bf16x8*)(dst + e) = r;
  }
}

// convert2: proj_w (f32, 589824) -> bf16 (into dead Q region).
__global__ __launch_bounds__(256) void convert2_kernel(
    const float* __restrict__ w, bf16* __restrict__ dst)
{
  size_t i = (size_t)blockIdx.x * 256 + threadIdx.x;
  size_t e = i * 8;
  if (e >= 589824) return;
  f32x4 a = *(const f32x4*)(w + e);
  f32x4 b = *(const f32x4*)(w + e + 4);
  bf16x8 r;
  r[0] = (bf16)a[0]; r[1] = (bf16)a[1]; r[2] = (bf16)a[2]; r[3] = (bf16)a[3];
  r[4] = (bf16)b[0]; r[5] = (bf16)b[1]; r[6] = (bf16)b[2]; r[7] = (bf16)b[3];
  *(bf16x8*)(dst + e) = r;
}

// ---------------------------------------------------------------------------
// Kernel 1: QKV projection, all-bf16, global_load_lds staging (m97 structure).
// 128x128 tile, BK=32, 4 waves each 64x64. Scatter epilogue into Q/K/V.
// ---------------------------------------------------------------------------
__global__ __launch_bounds__(256) void qkv_kernel(
    const bf16* __restrict__ X, const bf16* __restrict__ W,
    bf16* __restrict__ Qo, bf16* __restrict__ Ko, bf16* __restrict__ Vo)
{
  __shared__ bf16 As[128][32];   // linear, gload_lds dest
  __shared__ bf16 Bs[128][32];
  int bid = blockIdx.x;                    // 3456 blocks
  int swz = (bid & 7) * 432 + (bid >> 3);  // XCD-contiguous, bijective (3456%8==0)
  const int nt = swz % 18, mt = swz / 18;
  const int m0 = mt * 128, n0 = nt * 128;
  const int tid = threadIdx.x;
  const int lane = tid & 63;
  const int wv = tid >> 6;
  const int wr = (wv >> 1) * 64, wc = (wv & 1) * 64;
  const int lr = lane & 15, lg = lane >> 4;

  f32x4 acc[4][4] = {};

  for (int kt = 0; kt < 768; kt += 32) {
#pragma unroll
    for (int i = 0; i < 2; ++i) {
      int v = i * 256 + tid;               // 0..511; row=v>>2, col8=(v&3)*8
      int row = v >> 2, c8 = (v & 3) * 8;
      bf16* lbase = &As[0][0] + (size_t)(i * 256 + wv * 64) * 8;  // 16B/lane
      gload16(X + (size_t)(m0 + row) * 768 + kt + c8, lbase);
      bf16* lbase2 = &Bs[0][0] + (size_t)(i * 256 + wv * 64) * 8;
      gload16(W + (size_t)(n0 + row) * 768 + kt + c8, lbase2);
    }
    __syncthreads();     // drains vmcnt -> LDS tiles ready
    bf16x8 af[4], bfr[4];
#pragma unroll
    for (int mf = 0; mf < 4; ++mf) af[mf] = *(const bf16x8*)(&As[wr + mf * 16 + lr][lg * 8]);
#pragma unroll
    for (int nf = 0; nf < 4; ++nf) bfr[nf] = *(const bf16x8*)(&Bs[wc + nf * 16 + lr][lg * 8]);
#pragma unroll
    for (int mf = 0; mf < 4; ++mf)
#pragma unroll
      for (int nf = 0; nf < 4; ++nf)
        acc[mf][nf] = MFMA16(af[mf], bfr[nf], acc[mf][nf]);
    __syncthreads();
  }

#pragma unroll
  for (int mf = 0; mf < 4; ++mf)
#pragma unroll
    for (int nf = 0; nf < 4; ++nf)
#pragma unroll
      for (int r = 0; r < 4; ++r) {
        int m = m0 + wr + mf * 16 + lg * 4 + r;
        int n = n0 + wc + nf * 16 + lr;
        int bp = m / 384, tok = m - bp * 384;
        int comp = (n >= 1536) ? 2 : (n >= 768) ? 1 : 0;
        int rem = n - comp * 768;
        int hh = rem >> 6, d = rem & 63;
        size_t addr = (((size_t)bp * 12 + hh) * 384 + tok) * 64 + d;
        float val = acc[mf][nf][r];
        if (comp == 0)      Qo[addr] = (bf16)(val * 0.125f);   // fold 1/sqrt(Dh)
        else if (comp == 1) Ko[addr] = (bf16)val;
        else                Vo[addr] = (bf16)val;
      }
}

// ---------------------------------------------------------------------------
// Kernel 2: attention (unchanged from round 2). grid = 64*12*3.
// ---------------------------------------------------------------------------
__global__ __launch_bounds__(256) void attn_kernel(
    const bf16* __restrict__ Q, const bf16* __restrict__ K, const bf16* __restrict__ V,
    bf16* __restrict__ ATT)
{
  __shared__ union {
    bf16 Qs[128][72];
    bf16 Ps[4][32][136];     // per-wave P tile (Qs dead after qf reg-cache)
  } u;
  __shared__ bf16 Ks[128][72];
  __shared__ bf16 VTs[64][136];     // transposed V: [d][token]

  const int bid = blockIdx.x;
  const int qb = bid % 3;
  const int h  = (bid / 3) % 12;
  const int bp = bid / 36;           // b' in [0,64)
  const int tid = threadIdx.x;
  const int lane = tid & 63;
  const int wv = tid >> 6;
  const int lr = lane & 15, lg = lane >> 4;

  const size_t bh384 = ((size_t)bp * 12 + h) * 384;
  const int q0 = qb * 128;

  for (int v = tid; v < 1024; v += 256) {
    int row = v >> 3, cg = (v & 7) * 8;
    *(bf16x8*)(&u.Qs[row][cg]) = *(const bf16x8*)(Q + (bh384 + q0 + row) * 64 + cg);
  }
  __syncthreads();

  bf16x8 qf[2][2];
#pragma unroll
  for (int mf = 0; mf < 2; ++mf)
#pragma unroll
    for (int ks = 0; ks < 2; ++ks)
      qf[mf][ks] = *(const bf16x8*)(&u.Qs[wv * 32 + mf * 16 + lr][ks * 32 + lg * 8]);

  f32x4 O[2][4] = {};
  float runmax[2][4], runsum[2][4];
#pragma unroll
  for (int mf = 0; mf < 2; ++mf)
#pragma unroll
    for (int r = 0; r < 4; ++r) { runmax[mf][r] = -1e30f; runsum[mf][r] = 0.f; }

  const int nchunks = (qb == 0) ? 1 : 4;
  for (int c = 0; c < nchunks; ++c) {
    int src_b, t0;
    if (qb == 0)      { src_b = bp;            t0 = 0; }
    else if (c == 0)  { src_b = bp & 31;       t0 = 0; }          // mt of V batch
    else if (c == 1)  { src_b = (bp & 31)+32;  t0 = 0; }          // mt of I batch
    else              { src_b = bp;            t0 = (c - 1) * 128; } // own s tokens
    const size_t kb = (((size_t)src_b * 12 + h) * 384 + t0) * 64;

    __syncthreads();   // previous chunk fully consumed before restaging
    for (int v = tid; v < 1024; v += 256) {
      int row = v >> 3, cg = (v & 7) * 8;
      *(bf16x8*)(&Ks[row][cg]) = *(const bf16x8*)(K + kb + row * 64 + cg);
      bf16x8 vvld = *(const bf16x8*)(V + kb + row * 64 + cg);
#pragma unroll
      for (int j = 0; j < 8; ++j) VTs[cg + j][row] = vvld[j];
    }
    __syncthreads();

    // S = Q * Kc^T   (scale already folded into Q)
    f32x4 S[2][8] = {};
#pragma unroll
    for (int nf = 0; nf < 8; ++nf) {
#pragma unroll
      for (int ks = 0; ks < 2; ++ks) {
        bf16x8 kf = *(const bf16x8*)(&Ks[nf * 16 + lr][ks * 32 + lg * 8]);
        S[0][nf] = MFMA16(qf[0][ks], kf, S[0][nf]);
        S[1][nf] = MFMA16(qf[1][ks], kf, S[1][nf]);
      }
    }

    // online softmax (row = lg*4 + r within 16-row fragment; 16-lane reduce)
#pragma unroll
    for (int mf = 0; mf < 2; ++mf) {
#pragma unroll
      for (int r = 0; r < 4; ++r) {
        float mx = S[mf][0][r];
#pragma unroll
        for (int nf = 1; nf < 8; ++nf) mx = fmaxf(mx, S[mf][nf][r]);
        mx = fmaxf(mx, __shfl_xor(mx, 1));
        mx = fmaxf(mx, __shfl_xor(mx, 2));
        mx = fmaxf(mx, __shfl_xor(mx, 4));
        mx = fmaxf(mx, __shfl_xor(mx, 8));
        float nm = fmaxf(runmax[mf][r], mx);
        float rf = __expf(runmax[mf][r] - nm);
        float rs = 0.f;
#pragma unroll
        for (int nf = 0; nf < 8; ++nf) {
          float p = __expf(S[mf][nf][r] - nm);
          S[mf][nf][r] = p;
          rs += p;
        }
        rs += __shfl_xor(rs, 1);
        rs += __shfl_xor(rs, 2);
        rs += __shfl_xor(rs, 4);
        rs += __shfl_xor(rs, 8);
        runsum[mf][r] = runsum[mf][r] * rf + rs;
        runmax[mf][r] = nm;
#pragma unroll
        for (int vn = 0; vn < 4; ++vn) O[mf][vn][r] *= rf;
      }
    }

    // P (C-layout) -> LDS -> A-layout fragments.  Wave-private; DS in-order.
#pragma unroll
    for (int mf = 0; mf < 2; ++mf)
#pragma unroll
      for (int nf = 0; nf < 8; ++nf)
#pragma unroll
        for (int r = 0; r < 4; ++r)
          u.Ps[wv][mf * 16 + lg * 4 + r][nf * 16 + lr] = (bf16)S[mf][nf][r];

#pragma unroll
    for (int ks = 0; ks < 4; ++ks) {
      bf16x8 pf0 = *(const bf16x8*)(&u.Ps[wv][lr][ks * 32 + lg * 8]);
      bf16x8 pf1 = *(const bf16x8*)(&u.Ps[wv][16 + lr][ks * 32 + lg * 8]);
#pragma unroll
      for (int vn = 0; vn < 4; ++vn) {
        bf16x8 vf = *(const bf16x8*)(&VTs[vn * 16 + lr][ks * 32 + lg * 8]);
        O[0][vn] = MFMA16(pf0, vf, O[0][vn]);
        O[1][vn] = MFMA16(pf1, vf, O[1][vn]);
      }
    }
  }

#pragma unroll
  for (int mf = 0; mf < 2; ++mf)
#pragma unroll
    for (int vn = 0; vn < 4; ++vn)
#pragma unroll
      for (int r = 0; r < 4; ++r) {
        int tok = q0 + wv * 32 + mf * 16 + lg * 4 + r;
        int d = vn * 16 + lr;
        float o = O[mf][vn][r] / runsum[mf][r];
        ATT[((size_t)bp * 384 + tok) * 768 + h * 64 + d] = (bf16)o;
      }
}

// ---------------------------------------------------------------------------
// Kernel 3: output projection, bf16 inputs via global_load_lds, f32 out+bias.
// ---------------------------------------------------------------------------
__global__ __launch_bounds__(256) void proj_kernel(
    const bf16* __restrict__ A, const bf16* __restrict__ W,
    const float* __restrict__ bias, float* __restrict__ out)
{
  __shared__ bf16 As[128][32];
  __shared__ bf16 Bs[128][32];
  int bid = blockIdx.x;                    // 1152 blocks
  int swz = (bid & 7) * 144 + (bid >> 3);  // 1152/8 = 144
  const int nt = swz % 6, mt = swz / 6;
  const int m0 = mt * 128, n0 = nt * 128;
  const int tid = threadIdx.x;
  const int lane = tid & 63;
  const int wv = tid >> 6;
  const int wr = (wv >> 1) * 64, wc = (wv & 1) * 64;
  const int lr = lane & 15, lg = lane >> 4;

  f32x4 acc[4][4] = {};

  for (int kt = 0; kt < 768; kt += 32) {
#pragma unroll
    for (int i = 0; i < 2; ++i) {
      int v = i * 256 + tid;
      int row = v >> 2, c8 = (v & 3) * 8;
      bf16* lbase = &As[0][0] + (size_t)(i * 256 + wv * 64) * 8;
      gload16(A + (size_t)(m0 + row) * 768 + kt + c8, lbase);
      bf16* lbase2 = &Bs[0][0] + (size_t)(i * 256 + wv * 64) * 8;
      gload16(W + (size_t)(n0 + row) * 768 + kt + c8, lbase2);
    }
    __syncthreads();
    bf16x8 af[4], bfr[4];
#pragma unroll
    for (int mf = 0; mf < 4; ++mf) af[mf] = *(const bf16x8*)(&As[wr + mf * 16 + lr][lg * 8]);
#pragma unroll
    for (int nf = 0; nf < 4; ++nf) bfr[nf] = *(const bf16x8*)(&Bs[wc + nf * 16 + lr][lg * 8]);
#pragma unroll
    for (int mf = 0; mf < 4; ++mf)
#pragma unroll
      for (int nf = 0; nf < 4; ++nf)
        acc[mf][nf] = MFMA16(af[mf], bfr[nf], acc[mf][nf]);
    __syncthreads();
  }

#pragma unroll
  for (int mf = 0; mf < 4; ++mf)
#pragma unroll
    for (int nf = 0; nf < 4; ++nf)
#pragma unroll
      for (int r = 0; r < 4; ++r) {
        int m = m0 + wr + mf * 16 + lg * 4 + r;
        int n = n0 + wc + nf * 16 + lr;
        out[(size_t)m * 768 + n] = acc[mf][nf][r] + bias[n];
      }
}

// ---------------------------------------------------------------------------
extern "C" void kernel_launch(void* const* d_in, const int* in_sizes, int n_in,
                              void* d_out, int out_size, void* d_ws, size_t ws_size,
                              hipStream_t stream) {
  (void)in_sizes; (void)n_in; (void)out_size; (void)ws_size;
  const float* xv     = (const float*)d_in[0];
  const float* xi     = (const float*)d_in[1];
  const float* qkv_w  = (const float*)d_in[2];
  const float* proj_w = (const float*)d_in[3];
  const float* proj_b = (const float*)d_in[4];
  float* out = (float*)d_out;

  // bf16 scratch inside d_out (75.5 MB): Xb [24576][768] then Wq [2304][768].
  bf16* Xb = (bf16*)d_out;
  bf16* Wq = Xb + (size_t)18874368;

  // ws: Q | K | V | ATT, each 18874368 bf16 (~36 MB) = 151 MB total.
  const size_t SZ = (size_t)64 * 12 * 384 * 64;
  bf16* Q   = (bf16*)d_ws;
  bf16* K   = Q + SZ;
  bf16* V   = K + SZ;
  bf16* ATT = V + SZ;
  bf16* Wp  = Q;                 // proj_w bf16, reuses Q region after attn

  convert1_kernel<<<2048, 256, 0, stream>>>(xv, xi, qkv_w, Xb);
  qkv_kernel<<<3456, 256, 0, stream>>>(Xb, Wq, Q, K, V);
  attn_kernel<<<64 * 12 * 3, 256, 0, stream>>>(Q, K, V, ATT);
  convert2_kernel<<<288, 256, 0, stream>>>(proj_w, Wp);
  proj_kernel<<<1152, 256, 0, stream>>>(ATT, Wp, proj_b, out);
}